// Round 1
// baseline (281.340 us; speedup 1.0000x reference)
//
#include <hip/hip_runtime.h>
#include <hip/hip_bf16.h>
#include <stdint.h>

typedef __bf16 bf16x8 __attribute__((ext_vector_type(8)));
typedef uint16_t u16x8 __attribute__((ext_vector_type(8)));
typedef float f32x16 __attribute__((ext_vector_type(16)));

// DIMS = 256 ->128 ->256 ->512 ->256 ->128 ->64 ->32 ->16 ->10
static constexpr int KD[9]    = {256,128,256,512,256,128,64,32,16};   // layer input width
static constexpr int ND[9]    = {128,256,512,256,128,64,32,16,10};   // layer output width
static constexpr int NPD[9]   = {128,256,512,256,128,64,32,32,32};   // output padded to 32
static constexpr int WOFF[10] = {0,32768,65536,196608,327680,360448,368640,370688,371712,372224};
static constexpr int BOFF[10] = {0,128,384,896,1152,1280,1344,1376,1408,1440};
static constexpr int WTOT = 372224;   // bf16 elements of transposed weights in ws
static constexpr int BTOT = 1440;     // padded bias floats in ws

__device__ __forceinline__ uint16_t f2bf(float f) {
  uint32_t u = __builtin_bit_cast(uint32_t, f);
  return (uint16_t)((u + 0x7fffu + ((u >> 16) & 1u)) >> 16);   // RNE
}

// ---------------- prep: W[K][N] fp32 -> Wt[Npad][K] bf16 (+ padded bias) ----------------
struct PrepArgs {
  const float* W[9];
  const float* b[9];
  uint16_t* wt;
  float* bias;
};

__global__ void prep_kernel(PrepArgs a) {
  int idx = blockIdx.x * 256 + threadIdx.x;
  if (idx < WTOT) {
#pragma unroll
    for (int l = 0; l < 9; ++l) {
      if (idx >= WOFF[l] && idx < WOFF[l + 1]) {
        const int K = KD[l], N = ND[l];
        int local = idx - WOFF[l];
        int n = local / K;
        int k = local - n * K;
        float v = (n < N) ? a.W[l][(size_t)k * N + n] : 0.0f;
        a.wt[idx] = f2bf(v);
      }
    }
  } else if (idx < WTOT + BTOT) {
    int bidx = idx - WTOT;
#pragma unroll
    for (int l = 0; l < 9; ++l) {
      if (bidx >= BOFF[l] && bidx < BOFF[l + 1]) {
        int n = bidx - BOFF[l];
        a.bias[bidx] = (n < ND[l]) ? a.b[l][n] : 0.0f;
      }
    }
  }
}

// ---------------- fused MLP ----------------
struct MainArgs {
  const float* x;
  const float* m[8];
  const uint16_t* wt;
  const float* bias;
  float* out;
};

// A-frag (32x32x16 bf16): lane holds row=lane&31, k = (lane>>5)*8 + [0..7]  (contiguous)
// B-frag:                  lane holds col=lane&31, k = (lane>>5)*8 + [0..7]
// C/D  :                   col=lane&31, row=(reg&3)+8*(reg>>2)+4*(lane>>5)   [m74/m101]
template <int L, bool LAST>
__device__ __forceinline__ void layer_fn(const MainArgs& a, int row0, int wid, int lane,
                                         const char* inb, char* outb) {
  constexpr int K   = KD[L];
  constexpr int N   = ND[L];
  constexpr int NP  = NPD[L];
  constexpr int SWZI = (K >= 64) ? 7 : (K == 32 ? 3 : 1);   // keep XOR bits inside a row
  constexpr int SWZO = (N >= 64) ? 7 : (N == 32 ? 3 : 1);
  constexpr int TN  = NP / 32;
  constexpr int NB  = (TN >= 4) ? (TN / 4) : 1;             // col-tiles per wave
  constexpr int ACT = (TN >= 4) ? 4 : TN;                   // active waves
  constexpr int KS  = K / 16;

  if (wid < ACT) {
    const int r  = lane & 31;
    const int kg = lane >> 5;
    const int ct0 = wid * NB;
    const uint16_t* wbase = a.wt + WOFF[L];

    f32x16 acc[NB];
#pragma unroll
    for (int i = 0; i < NB; ++i)
#pragma unroll
      for (int t = 0; t < 16; ++t) acc[i][t] = 0.0f;

    if constexpr (NB == 1 && KS >= 2) {
      // split-K: two independent accumulator chains
      f32x16 acc2;
#pragma unroll
      for (int t = 0; t < 16; ++t) acc2[t] = 0.0f;
      const uint16_t* bp = wbase + ((size_t)(ct0 * 32 + r) * K + kg * 8);
#pragma unroll
      for (int ks = 0; ks < KS; ks += 2) {
        uint32_t ab0 = (uint32_t)(r * K + ks * 16 + kg * 8) * 2;
        ab0 ^= (uint32_t)(r & SWZI) << 4;
        bf16x8 a0 = *(const bf16x8*)(inb + ab0);
        bf16x8 b0 = *(const bf16x8*)(bp + ks * 16);
        acc[0] = __builtin_amdgcn_mfma_f32_32x32x16_bf16(a0, b0, acc[0], 0, 0, 0);

        uint32_t ab1 = (uint32_t)(r * K + (ks + 1) * 16 + kg * 8) * 2;
        ab1 ^= (uint32_t)(r & SWZI) << 4;
        bf16x8 a1 = *(const bf16x8*)(inb + ab1);
        bf16x8 b1 = *(const bf16x8*)(bp + (ks + 1) * 16);
        acc2 = __builtin_amdgcn_mfma_f32_32x32x16_bf16(a1, b1, acc2, 0, 0, 0);
      }
      acc[0] += acc2;
    } else {
#pragma unroll
      for (int ks = 0; ks < KS; ++ks) {
        uint32_t ab = (uint32_t)(r * K + ks * 16 + kg * 8) * 2;
        ab ^= (uint32_t)(r & SWZI) << 4;
        bf16x8 av = *(const bf16x8*)(inb + ab);
#pragma unroll
        for (int i = 0; i < NB; ++i) {
          const uint16_t* bp = wbase + ((size_t)((ct0 + i) * 32 + r) * K + ks * 16 + kg * 8);
          bf16x8 bv = *(const bf16x8*)bp;
          acc[i] = __builtin_amdgcn_mfma_f32_32x32x16_bf16(av, bv, acc[i], 0, 0, 0);
        }
      }
    }

    // epilogue: bias -> (relu*mask -> LDS bf16) | (store fp32)
    const float* biasb = a.bias + BOFF[L];
#pragma unroll
    for (int i = 0; i < NB; ++i) {
      const int col = (ct0 + i) * 32 + r;
      const float bv = biasb[col];
#pragma unroll
      for (int t = 0; t < 16; ++t) {
        const int rit = (t & 3) + ((t >> 2) << 3) + (kg << 2);
        float v = acc[i][t] + bv;
        if constexpr (LAST) {
          if (col < N) a.out[(size_t)(row0 + rit) * N + col] = v;
        } else {
          v = fmaxf(v, 0.0f);
          if (N == NP || col < N) {
            v *= a.m[L][(size_t)(row0 + rit) * N + col];
            uint32_t ob = (uint32_t)(rit * N + col) * 2;
            ob ^= (uint32_t)(rit & SWZO) << 4;
            *(uint16_t*)(outb + ob) = f2bf(v);
          }
        }
      }
    }
  }
}

__global__ __launch_bounds__(256, 3) void mlp_kernel(MainArgs a) {
  __shared__ char lds[49152];
  char* buf0 = lds;            // holds widths <= 256 (x, L1-out, L3-out, L5-out, L7-out)
  char* buf1 = lds + 16384;    // holds widths <= 512

  const int tid = threadIdx.x;
  const int row0 = blockIdx.x * 32;

  // stage x: fp32 -> bf16 into buf0 (swizzled), coalesced 32B/thread/iter
  {
    const float* xp = a.x + (size_t)row0 * 256;
#pragma unroll
    for (int j = 0; j < 4; ++j) {
      const int cidx = j * 256 + tid;       // float8 chunk id in [0,1024)
      const int rr = cidx >> 5;             // row 0..31
      const int cc = (cidx & 31) << 3;      // col 0..248
      const float4 f0 = *(const float4*)(xp + cidx * 8);
      const float4 f1 = *(const float4*)(xp + cidx * 8 + 4);
      u16x8 h;
      h[0] = f2bf(f0.x); h[1] = f2bf(f0.y); h[2] = f2bf(f0.z); h[3] = f2bf(f0.w);
      h[4] = f2bf(f1.x); h[5] = f2bf(f1.y); h[6] = f2bf(f1.z); h[7] = f2bf(f1.w);
      uint32_t byte = (uint32_t)(rr * 512 + cc * 2);
      byte ^= (uint32_t)(rr & 7) << 4;
      *(u16x8*)(buf0 + byte) = h;
    }
  }
  __syncthreads();

  const int lane = tid & 63;
  const int wid = tid >> 6;

  layer_fn<0, false>(a, row0, wid, lane, buf0, buf1); __syncthreads();
  layer_fn<1, false>(a, row0, wid, lane, buf1, buf0); __syncthreads();
  layer_fn<2, false>(a, row0, wid, lane, buf0, buf1); __syncthreads();
  layer_fn<3, false>(a, row0, wid, lane, buf1, buf0); __syncthreads();
  layer_fn<4, false>(a, row0, wid, lane, buf0, buf1); __syncthreads();
  layer_fn<5, false>(a, row0, wid, lane, buf1, buf0); __syncthreads();
  layer_fn<6, false>(a, row0, wid, lane, buf0, buf1); __syncthreads();
  layer_fn<7, false>(a, row0, wid, lane, buf1, buf0); __syncthreads();
  layer_fn<8, true >(a, row0, wid, lane, buf0, buf1);
}

extern "C" void kernel_launch(void* const* d_in, const int* in_sizes, int n_in,
                              void* d_out, int out_size, void* d_ws, size_t ws_size,
                              hipStream_t stream) {
  (void)in_sizes; (void)n_in; (void)out_size; (void)ws_size;

  PrepArgs pa;
  for (int l = 0; l < 9; ++l) {
    pa.W[l] = (const float*)d_in[1 + 2 * l];
    pa.b[l] = (const float*)d_in[2 + 2 * l];
  }
  uint16_t* wt = (uint16_t*)d_ws;
  float* bias = (float*)((char*)d_ws + (size_t)WTOT * 2);
  pa.wt = wt;
  pa.bias = bias;
  prep_kernel<<<dim3((WTOT + BTOT + 255) / 256), dim3(256), 0, stream>>>(pa);

  MainArgs ma;
  ma.x = (const float*)d_in[0];
  for (int i = 0; i < 8; ++i) ma.m[i] = (const float*)d_in[19 + i];
  ma.wt = wt;
  ma.bias = bias;
  ma.out = (float*)d_out;
  mlp_kernel<<<dim3(65536 / 32), dim3(256), 0, stream>>>(ma);
}

// Round 2
// 266.929 us; speedup vs baseline: 1.0540x; 1.0540x over previous
//
#include <hip/hip_runtime.h>
#include <hip/hip_bf16.h>
#include <stdint.h>

typedef __bf16 bf16x8 __attribute__((ext_vector_type(8)));
typedef uint16_t u16x8 __attribute__((ext_vector_type(8)));
typedef float f32x16 __attribute__((ext_vector_type(16)));

// DIMS = 256 ->128 ->256 ->512 ->256 ->128 ->64 ->32 ->16 ->10
static constexpr int KD[9]    = {256,128,256,512,256,128,64,32,16};   // layer input width
static constexpr int ND[9]    = {128,256,512,256,128,64,32,16,10};   // layer output width
static constexpr int WOFF[10] = {0,32768,65536,196608,327680,360448,368640,370688,371712,372224};
static constexpr int BOFF[10] = {0,128,384,896,1152,1280,1344,1376,1408,1440};
static constexpr int WTOT = 372224;   // bf16 elements of transposed weights in ws
static constexpr int BTOT = 1440;     // padded bias floats in ws

__device__ __forceinline__ uint16_t f2bf(float f) {
  uint32_t u = __builtin_bit_cast(uint32_t, f);
  return (uint16_t)((u + 0x7fffu + ((u >> 16) & 1u)) >> 16);   // RNE
}

// ---------------- prep: W[K][N] fp32 -> Wt[Npad][K] bf16 (+ padded bias) ----------------
struct PrepArgs {
  const float* W[9];
  const float* b[9];
  uint16_t* wt;
  float* bias;
};

__global__ void prep_kernel(PrepArgs a) {
  int idx = blockIdx.x * 256 + threadIdx.x;
  if (idx < WTOT) {
#pragma unroll
    for (int l = 0; l < 9; ++l) {
      if (idx >= WOFF[l] && idx < WOFF[l + 1]) {
        const int K = KD[l], N = ND[l];
        int local = idx - WOFF[l];
        int n = local / K;
        int k = local - n * K;
        float v = (n < N) ? a.W[l][(size_t)k * N + n] : 0.0f;
        a.wt[idx] = f2bf(v);
      }
    }
  } else if (idx < WTOT + BTOT) {
    int bidx = idx - WTOT;
#pragma unroll
    for (int l = 0; l < 9; ++l) {
      if (bidx >= BOFF[l] && bidx < BOFF[l + 1]) {
        int n = bidx - BOFF[l];
        a.bias[bidx] = (n < ND[l]) ? a.b[l][n] : 0.0f;
      }
    }
  }
}

// ---------------- fused MLP ----------------
struct MainArgs {
  const float* x;
  const float* m[8];
  const uint16_t* wt;
  const float* bias;
  float* out;
};

// A-frag (32x32x16 bf16): lane holds row=lane&31, k = (lane>>5)*8 + [0..7]
// B-frag:                  lane holds col=lane&31, k = (lane>>5)*8 + [0..7]
// C/D  :                   col=lane&31, row=(reg&3)+8*(reg>>2)+4*(lane>>5)   [m74/m101]
//
// TNE = number of 32-col tiles this call computes; CTOFF = tile offset (for split L2).
// SIN: input is split across two 16KB half-buffers (L3, K=512).
// PREBAR: barrier between compute and epilogue-write (write aliases input buffer).
template <int L, int TNE, int CTOFF, bool LAST, bool SIN, bool PREBAR, int OSTR>
__device__ __forceinline__ void layer_fn(const MainArgs& a, int row0, int wid, int lane,
                                         const char* in0, const char* in1, char* outb) {
  constexpr int K   = KD[L];
  constexpr int N   = ND[L];
  constexpr int KS  = K / 16;
  constexpr int NB  = (TNE >= 4) ? TNE / 4 : 1;
  constexpr int ACT = (TNE >= 4) ? 4 : TNE;
  constexpr int SWZI = (K >= 64) ? 7 : (K == 32 ? 3 : 1);
  constexpr int SWZO = (OSTR >= 64) ? 7 : (OSTR == 32 ? 3 : 1);
  constexpr bool DUAL = (NB == 1 && KS >= 2);

  const int r  = lane & 31;
  const int kg = lane >> 5;
  const int ct0 = wid * NB;
  const bool act = (wid < ACT);

  f32x16 acc[NB];
  f32x16 acc2;
  float mv[NB][16];
  float bvv[NB];

  if (act) {
#pragma unroll
    for (int i = 0; i < NB; ++i)
#pragma unroll
      for (int t = 0; t < 16; ++t) acc[i][t] = 0.0f;
    if constexpr (DUAL) {
#pragma unroll
      for (int t = 0; t < 16; ++t) acc2[t] = 0.0f;
    }

    // prefetch bias + dropout masks BEFORE the MFMA chain (HBM latency cover)
#pragma unroll
    for (int i = 0; i < NB; ++i) {
      const int col = (CTOFF + ct0 + i) * 32 + r;
      bvv[i] = a.bias[BOFF[L] + col];
      if constexpr (!LAST) {
        const int mc = (N % 32) ? (col < N ? col : N - 1) : col;
        const float* mrow = a.m[L] + mc;
#pragma unroll
        for (int t = 0; t < 16; ++t) {
          const int rit = (t & 3) + ((t >> 2) << 3) + (kg << 2);
          mv[i][t] = mrow[(size_t)(row0 + rit) * N];
        }
      }
    }

    const uint16_t* bp[NB];
#pragma unroll
    for (int i = 0; i < NB; ++i)
      bp[i] = a.wt + WOFF[L] + (size_t)((CTOFF + ct0 + i) * 32 + r) * K + kg * 8;

    // B-fragment double buffer
    bf16x8 bb[2][NB];
#pragma unroll
    for (int i = 0; i < NB; ++i) bb[0][i] = *(const bf16x8*)bp[i];

#pragma unroll
    for (int ks = 0; ks < KS; ++ks) {
      if (ks + 1 < KS) {
#pragma unroll
        for (int i = 0; i < NB; ++i)
          bb[(ks + 1) & 1][i] = *(const bf16x8*)(bp[i] + (ks + 1) * 16);
      }
      bf16x8 av;
      {
        uint32_t byte;
        const char* src;
        if constexpr (SIN) {
          const int kk = (ks < 16) ? ks : ks - 16;
          src = (ks < 16) ? in0 : in1;
          byte = (uint32_t)(r * 256 + kk * 16 + kg * 8) * 2;
          byte ^= (uint32_t)(r & 7) << 4;
        } else {
          src = in0;
          byte = (uint32_t)(r * K + ks * 16 + kg * 8) * 2;
          byte ^= (uint32_t)(r & SWZI) << 4;
        }
        av = *(const bf16x8*)(src + byte);
      }
      if constexpr (DUAL) {
        if ((ks & 1) == 0)
          acc[0] = __builtin_amdgcn_mfma_f32_32x32x16_bf16(av, bb[ks & 1][0], acc[0], 0, 0, 0);
        else
          acc2 = __builtin_amdgcn_mfma_f32_32x32x16_bf16(av, bb[ks & 1][0], acc2, 0, 0, 0);
      } else {
#pragma unroll
        for (int i = 0; i < NB; ++i)
          acc[i] = __builtin_amdgcn_mfma_f32_32x32x16_bf16(av, bb[ks & 1][i], acc[i], 0, 0, 0);
      }
    }
    if constexpr (DUAL) acc[0] += acc2;
  }

  if constexpr (PREBAR) __syncthreads();

  if (act) {
#pragma unroll
    for (int i = 0; i < NB; ++i) {
      const int col = (CTOFF + ct0 + i) * 32 + r;
#pragma unroll
      for (int t = 0; t < 16; ++t) {
        const int rit = (t & 3) + ((t >> 2) << 3) + (kg << 2);
        float v = acc[i][t] + bvv[i];
        if constexpr (LAST) {
          if (col < N) a.out[(size_t)(row0 + rit) * N + col] = v;
        } else {
          v = fmaxf(v, 0.0f) * mv[i][t];
          if ((N % 32 == 0) || col < N) {
            uint32_t ob = (uint32_t)(rit * OSTR + (col - CTOFF * 32)) * 2;
            ob ^= (uint32_t)(rit & SWZO) << 4;
            *(uint16_t*)(outb + ob) = f2bf(v);
          }
        }
      }
    }
  }
}

__global__ __launch_bounds__(256, 4) void mlp_kernel(MainArgs a) {
  __shared__ char bufA[16384];
  __shared__ char bufB[16384];

  const int tid = threadIdx.x;
  const int row0 = blockIdx.x * 32;

  // stage x: fp32 -> bf16 into bufA (swizzled), coalesced 32B/thread/iter
  {
    const float* xp = a.x + (size_t)row0 * 256;
#pragma unroll
    for (int j = 0; j < 4; ++j) {
      const int cidx = j * 256 + tid;       // float8 chunk id in [0,1024)
      const int rr = cidx >> 5;             // row 0..31
      const int cc = (cidx & 31) << 3;      // col 0..248
      const float4 f0 = *(const float4*)(xp + cidx * 8);
      const float4 f1 = *(const float4*)(xp + cidx * 8 + 4);
      u16x8 h;
      h[0] = f2bf(f0.x); h[1] = f2bf(f0.y); h[2] = f2bf(f0.z); h[3] = f2bf(f0.w);
      h[4] = f2bf(f1.x); h[5] = f2bf(f1.y); h[6] = f2bf(f1.z); h[7] = f2bf(f1.w);
      uint32_t byte = (uint32_t)(rr * 512 + cc * 2) ^ ((uint32_t)(rr & 7) << 4);
      *(u16x8*)(bufA + byte) = h;
    }
  }
  __syncthreads();

  const int lane = tid & 63;
  const int wid = tid >> 6;

  layer_fn<0, 4, 0, false, false, false, 128>(a, row0, wid, lane, bufA, nullptr, bufB); __syncthreads();
  layer_fn<1, 8, 0, false, false, false, 256>(a, row0, wid, lane, bufB, nullptr, bufA); __syncthreads();
  // L2 (256->512) split into two half-layers: cols 256-511 -> bufB (free), then
  // cols 0-255 -> bufA (aliases input: PREBAR inside before the write).
  layer_fn<2, 8, 8, false, false, false, 256>(a, row0, wid, lane, bufA, nullptr, bufB);
  layer_fn<2, 8, 0, false, false, true,  256>(a, row0, wid, lane, bufA, nullptr, bufA); __syncthreads();
  // L3 (512->256): K split across bufA (k 0-255) + bufB (k 256-511), write bufA after PREBAR.
  layer_fn<3, 8, 0, false, true,  true,  256>(a, row0, wid, lane, bufA, bufB, bufA); __syncthreads();
  layer_fn<4, 4, 0, false, false, false, 128>(a, row0, wid, lane, bufA, nullptr, bufB); __syncthreads();
  layer_fn<5, 2, 0, false, false, false, 64 >(a, row0, wid, lane, bufB, nullptr, bufA); __syncthreads();
  layer_fn<6, 1, 0, false, false, false, 32 >(a, row0, wid, lane, bufA, nullptr, bufB); __syncthreads();
  layer_fn<7, 1, 0, false, false, false, 16 >(a, row0, wid, lane, bufB, nullptr, bufA); __syncthreads();
  layer_fn<8, 1, 0, true,  false, false, 16 >(a, row0, wid, lane, bufA, nullptr, nullptr);
}

extern "C" void kernel_launch(void* const* d_in, const int* in_sizes, int n_in,
                              void* d_out, int out_size, void* d_ws, size_t ws_size,
                              hipStream_t stream) {
  (void)in_sizes; (void)n_in; (void)out_size; (void)ws_size;

  PrepArgs pa;
  for (int l = 0; l < 9; ++l) {
    pa.W[l] = (const float*)d_in[1 + 2 * l];
    pa.b[l] = (const float*)d_in[2 + 2 * l];
  }
  uint16_t* wt = (uint16_t*)d_ws;
  float* bias = (float*)((char*)d_ws + (size_t)WTOT * 2);
  pa.wt = wt;
  pa.bias = bias;
  prep_kernel<<<dim3((WTOT + BTOT + 255) / 256), dim3(256), 0, stream>>>(pa);

  MainArgs ma;
  ma.x = (const float*)d_in[0];
  for (int i = 0; i < 8; ++i) ma.m[i] = (const float*)d_in[19 + i];
  ma.wt = wt;
  ma.bias = bias;
  ma.out = (float*)d_out;
  mlp_kernel<<<dim3(65536 / 32), dim3(256), 0, stream>>>(ma);
}

// Round 3
// 143.327 us; speedup vs baseline: 1.9629x; 1.8624x over previous
//
#include <hip/hip_runtime.h>
#include <hip/hip_bf16.h>
#include <stdint.h>

typedef __bf16 bf16x8 __attribute__((ext_vector_type(8)));
typedef uint16_t u16x8 __attribute__((ext_vector_type(8)));
typedef float f32x16 __attribute__((ext_vector_type(16)));

// DIMS = 256 ->128 ->256 ->512 ->256 ->128 ->64 ->32 ->16 ->10
static constexpr int KD[9]    = {256,128,256,512,256,128,64,32,16};   // layer input width
static constexpr int ND[9]    = {128,256,512,256,128,64,32,16,10};   // layer output width
static constexpr int NPD[9]   = {128,256,512,256,128,64,32,32,32};   // output padded to 32
static constexpr int WOFF[10] = {0,32768,65536,196608,327680,360448,368640,370688,371712,372224};
static constexpr int BOFF[10] = {0,128,384,896,1152,1280,1344,1376,1408,1440};
static constexpr int WTOT = 372224;   // bf16 elements of fragment-ordered weights in ws
static constexpr int BTOT = 1440;     // padded bias floats in ws

__device__ __forceinline__ uint16_t f2bf(float f) {
  uint32_t u = __builtin_bit_cast(uint32_t, f);
  return (uint16_t)((u + 0x7fffu + ((u >> 16) & 1u)) >> 16);   // RNE
}

// swizzle mask for a row-major LDS tile with rowbytes = width*2
constexpr int swzm(int width) {
  return (width >= 128) ? 15 : (width == 64) ? 7 : (width == 32) ? 3 : 1;
}

// ---------------- prep: W[K][N] fp32 -> B-fragment-ordered bf16 (+ padded bias) ----------
// Layout per layer: flat = ((ct*KS + ks)*64 + lane)*8 + j
//   col = ct*32 + (lane&31), k = ks*16 + (lane>>5)*8 + j
// so a wave's B-load for (ct,ks) is 64 lanes x 16B fully contiguous (1KB).
struct PrepArgs {
  const float* W[9];
  const float* b[9];
  uint16_t* wt;
  float* bias;
};

__global__ void prep_kernel(PrepArgs a) {
  int idx = blockIdx.x * 256 + threadIdx.x;
  if (idx < WTOT) {
#pragma unroll
    for (int l = 0; l < 9; ++l) {
      if (idx >= WOFF[l] && idx < WOFF[l + 1]) {
        const int K = KD[l], N = ND[l], KS = KD[l] / 16;
        int local = idx - WOFF[l];
        int j    = local & 7;
        int g    = local >> 3;
        int lane = g & 63;
        int gg   = g >> 6;
        int ks   = gg % KS;
        int ct   = gg / KS;
        int n = ct * 32 + (lane & 31);
        int k = ks * 16 + (lane >> 5) * 8 + j;
        float v = (n < N) ? a.W[l][(size_t)k * N + n] : 0.0f;
        a.wt[idx] = f2bf(v);
      }
    }
  } else if (idx < WTOT + BTOT) {
    int bidx = idx - WTOT;
#pragma unroll
    for (int l = 0; l < 9; ++l) {
      if (bidx >= BOFF[l] && bidx < BOFF[l + 1]) {
        int n = bidx - BOFF[l];
        a.bias[bidx] = (n < ND[l]) ? a.b[l][n] : 0.0f;
      }
    }
  }
}

// ---------------- fused MLP ----------------
struct MainArgs {
  const float* x;
  const float* m[8];
  const uint16_t* wt;
  const float* bias;
  float* out;
};

// A-frag (32x32x16 bf16): lane holds row=lane&31, k = (lane>>5)*8 + [0..7]
// B-frag:                  lane holds col=lane&31, k = (lane>>5)*8 + [0..7]
// C/D  :                   col=lane&31, row=(reg&3)+8*(reg>>2)+4*(lane>>5)   [m74/m101]
template <int L, int TNE, int CTOFF, bool LAST, bool SIN, bool PREBAR, int OSTR>
__device__ __forceinline__ void layer_fn(const MainArgs& a, int row0, int wid, int lane,
                                         const char* in0, const char* in1, char* outb) {
  constexpr int K   = KD[L];
  constexpr int N   = ND[L];
  constexpr int KS  = K / 16;
  constexpr int NB  = (TNE >= 4) ? TNE / 4 : 1;
  constexpr int ACT = (TNE >= 4) ? 4 : TNE;
  constexpr int SWZI = swzm(K);
  constexpr int SWZO = swzm(OSTR);
  constexpr bool DUAL = (NB == 1 && KS >= 2);

  const int r  = lane & 31;
  const int kg = lane >> 5;
  const int ct0 = wid * NB;
  const bool act = (wid < ACT);

  f32x16 acc[NB];
  f32x16 acc2;
  float mv[NB][16];
  float bvv[NB];

  if (act) {
#pragma unroll
    for (int i = 0; i < NB; ++i)
#pragma unroll
      for (int t = 0; t < 16; ++t) acc[i][t] = 0.0f;
    if constexpr (DUAL) {
#pragma unroll
      for (int t = 0; t < 16; ++t) acc2[t] = 0.0f;
    }

    // fragment-ordered B base: wave's load for (tile i, ks) is contiguous 1KB
    const uint16_t* wbase = a.wt + WOFF[L]
        + ((size_t)(CTOFF + ct0) * KS * 64 + lane) * 8;

    // B double buffer: issue bb[0] FIRST so the first MFMA's vmcnt wait
    // does not drain the mask prefetch behind it.
    bf16x8 bb[2][NB];
#pragma unroll
    for (int i = 0; i < NB; ++i)
      bb[0][i] = *(const bf16x8*)(wbase + (size_t)i * KS * 512);

    // prefetch bias + dropout masks (HBM) under the MFMA chain
#pragma unroll
    for (int i = 0; i < NB; ++i) {
      const int col = (CTOFF + ct0 + i) * 32 + r;
      bvv[i] = a.bias[BOFF[L] + col];
      if constexpr (!LAST) {
        const int mc = (N % 32) ? (col < N ? col : N - 1) : col;
        const float* mrow = a.m[L] + mc;
#pragma unroll
        for (int t = 0; t < 16; ++t) {
          const int rit = (t & 3) + ((t >> 2) << 3) + (kg << 2);
          mv[i][t] = mrow[(size_t)(row0 + rit) * N];
        }
      }
    }

#pragma unroll
    for (int ks = 0; ks < KS; ++ks) {
      if (ks + 1 < KS) {
#pragma unroll
        for (int i = 0; i < NB; ++i)
          bb[(ks + 1) & 1][i] =
              *(const bf16x8*)(wbase + (size_t)i * KS * 512 + (size_t)(ks + 1) * 512);
      }
      bf16x8 av;
      {
        uint32_t byte;
        const char* src;
        if constexpr (SIN) {
          const int kk = (ks < 16) ? ks : ks - 16;
          src = (ks < 16) ? in0 : in1;
          byte = (uint32_t)(r * 256 + kk * 16 + kg * 8) * 2;
          byte ^= (uint32_t)(r & 15) << 4;
        } else {
          src = in0;
          byte = (uint32_t)(r * K + ks * 16 + kg * 8) * 2;
          byte ^= (uint32_t)(r & SWZI) << 4;
        }
        av = *(const bf16x8*)(src + byte);
      }
      if constexpr (DUAL) {
        if ((ks & 1) == 0)
          acc[0] = __builtin_amdgcn_mfma_f32_32x32x16_bf16(av, bb[ks & 1][0], acc[0], 0, 0, 0);
        else
          acc2 = __builtin_amdgcn_mfma_f32_32x32x16_bf16(av, bb[ks & 1][0], acc2, 0, 0, 0);
      } else {
#pragma unroll
        for (int i = 0; i < NB; ++i)
          acc[i] = __builtin_amdgcn_mfma_f32_32x32x16_bf16(av, bb[ks & 1][i], acc[i], 0, 0, 0);
      }
    }
    if constexpr (DUAL) acc[0] += acc2;
  }

  if constexpr (PREBAR) __syncthreads();

  if (act) {
#pragma unroll
    for (int i = 0; i < NB; ++i) {
      const int col = (CTOFF + ct0 + i) * 32 + r;
#pragma unroll
      for (int t = 0; t < 16; ++t) {
        const int rit = (t & 3) + ((t >> 2) << 3) + (kg << 2);
        float v = acc[i][t] + bvv[i];
        if constexpr (LAST) {
          if (col < N) a.out[(size_t)(row0 + rit) * N + col] = v;
        } else {
          v = fmaxf(v, 0.0f) * mv[i][t];
          if ((N % 32 == 0) || col < N) {
            uint32_t ob = (uint32_t)(rit * OSTR + (col - CTOFF * 32)) * 2;
            ob ^= (uint32_t)(rit & SWZO) << 4;
            *(uint16_t*)(outb + ob) = f2bf(v);
          }
        }
      }
    }
  }
}

__global__ __launch_bounds__(256, 4) void mlp_kernel(MainArgs a) {
  __shared__ char bufA[16384];
  __shared__ char bufB[16384];

  const int tid = threadIdx.x;
  const int row0 = blockIdx.x * 32;

  // stage x: fp32 -> bf16 into bufA (swizzled), coalesced
  {
    const float* xp = a.x + (size_t)row0 * 256;
#pragma unroll
    for (int j = 0; j < 4; ++j) {
      const int cidx = j * 256 + tid;       // float8 chunk id in [0,1024)
      const int rr = cidx >> 5;             // row 0..31
      const int cc = (cidx & 31) << 3;      // col 0..248
      const float4 f0 = *(const float4*)(xp + cidx * 8);
      const float4 f1 = *(const float4*)(xp + cidx * 8 + 4);
      u16x8 h;
      h[0] = f2bf(f0.x); h[1] = f2bf(f0.y); h[2] = f2bf(f0.z); h[3] = f2bf(f0.w);
      h[4] = f2bf(f1.x); h[5] = f2bf(f1.y); h[6] = f2bf(f1.z); h[7] = f2bf(f1.w);
      uint32_t byte = (uint32_t)(rr * 512 + cc * 2) ^ ((uint32_t)(rr & 15) << 4);
      *(u16x8*)(bufA + byte) = h;
    }
  }
  __syncthreads();

  const int lane = tid & 63;
  const int wid = tid >> 6;

  layer_fn<0, 4, 0, false, false, false, 128>(a, row0, wid, lane, bufA, nullptr, bufB); __syncthreads();
  layer_fn<1, 8, 0, false, false, false, 256>(a, row0, wid, lane, bufB, nullptr, bufA); __syncthreads();
  // L2 (256->512) split: cols 256-511 -> bufB (free), then cols 0-255 -> bufA
  // (aliases input: PREBAR inside before the write).
  layer_fn<2, 8, 8, false, false, false, 256>(a, row0, wid, lane, bufA, nullptr, bufB);
  layer_fn<2, 8, 0, false, false, true,  256>(a, row0, wid, lane, bufA, nullptr, bufA); __syncthreads();
  // L3 (512->256): K split across bufA (k 0-255) + bufB (k 256-511), write bufA after PREBAR.
  layer_fn<3, 8, 0, false, true,  true,  256>(a, row0, wid, lane, bufA, bufB, bufA); __syncthreads();
  layer_fn<4, 4, 0, false, false, false, 128>(a, row0, wid, lane, bufA, nullptr, bufB); __syncthreads();
  layer_fn<5, 2, 0, false, false, false, 64 >(a, row0, wid, lane, bufB, nullptr, bufA); __syncthreads();
  // L6..L8: only wave 0 active; chain is wave-local -> no barriers needed.
  layer_fn<6, 1, 0, false, false, false, 32 >(a, row0, wid, lane, bufA, nullptr, bufB);
  layer_fn<7, 1, 0, false, false, false, 16 >(a, row0, wid, lane, bufB, nullptr, bufA);
  layer_fn<8, 1, 0, true,  false, false, 16 >(a, row0, wid, lane, bufA, nullptr, nullptr);
}

extern "C" void kernel_launch(void* const* d_in, const int* in_sizes, int n_in,
                              void* d_out, int out_size, void* d_ws, size_t ws_size,
                              hipStream_t stream) {
  (void)in_sizes; (void)n_in; (void)out_size; (void)ws_size;

  PrepArgs pa;
  for (int l = 0; l < 9; ++l) {
    pa.W[l] = (const float*)d_in[1 + 2 * l];
    pa.b[l] = (const float*)d_in[2 + 2 * l];
  }
  uint16_t* wt = (uint16_t*)d_ws;
  float* bias = (float*)((char*)d_ws + (size_t)WTOT * 2);
  pa.wt = wt;
  pa.bias = bias;
  prep_kernel<<<dim3((WTOT + BTOT + 255) / 256), dim3(256), 0, stream>>>(pa);

  MainArgs ma;
  ma.x = (const float*)d_in[0];
  for (int i = 0; i < 8; ++i) ma.m[i] = (const float*)d_in[19 + i];
  ma.wt = wt;
  ma.bias = bias;
  ma.out = (float*)d_out;
  mlp_kernel<<<dim3(65536 / 32), dim3(256), 0, stream>>>(ma);
}